// Round 1
// 409.005 us; speedup vs baseline: 1.0841x; 1.0841x over previous
//
#include <hip/hip_runtime.h>

// Attend: out = softmax(causal(Q K^T * 0.125 + bias)) @ V
// B=4,H=16,N=1024,D=64. fp32 I/O, bf16 MFMA compute.
// Block = 64 q-rows of one head; 4 waves x 16 rows; j-tiles of 64.
// Round 1: software-pipelined. All global loads (K/V/bias) for tile jt+1
// are issued at the top of compute(jt) into registers; staging between the
// two barriers is pure cvt+ds_write. f2bf bit-twiddle replaced with HW
// v_cvt_pk_bf16_f32 (same RNE rounding). launch_bounds(256,4) caps VGPR=128.

#define BHn 64
#define Nn 1024
#define Dn 64
#define NEG_BIG (-1e30f)

typedef __attribute__((ext_vector_type(8))) short short8;
typedef __attribute__((ext_vector_type(4))) float floatx4;
typedef __attribute__((ext_vector_type(2))) unsigned uint2v;
typedef __attribute__((ext_vector_type(4))) unsigned uint4v;

__device__ __forceinline__ unsigned cvt_pk_bf16(float lo, float hi) {
    unsigned r;
    asm("v_cvt_pk_bf16_f32 %0, %1, %2" : "=v"(r) : "v"(lo), "v"(hi));
    return r;   // packed {bf16(lo), bf16(hi)}, RNE
}

__global__ __launch_bounds__(256, 4) void attend_mfma(
    const float* __restrict__ q, const float* __restrict__ kk,
    const float* __restrict__ v, const float* __restrict__ bias,
    float* __restrict__ out)
{
    const int bh = blockIdx.x >> 4;
    const int qt = 15 - (blockIdx.x & 15);   // long blocks dispatched first
    const int i0 = qt * 64;
    const int tid  = threadIdx.x;
    const int lane = tid & 63;
    const int wave = tid >> 6;
    const int ln = lane & 15;                // MFMA n / m index
    const int lg = lane >> 4;                // MFMA k-group / row-group

    // stride 80 shorts = 160 B: 16B-aligned rows.
    __shared__ short k_s[64][80];            // K tile, row-major [j][d]
    __shared__ short vt_s[64][80];           // V tile, transposed [d][j]
    __shared__ short p_s[4][16][80];         // per-wave P tile [m][j]

    // ---- preload Q A-frags (2 k-parts of K=32), fp32 -> bf16 ----
    short8 qa[2];
    {
        const float* qp = q + ((long)(bh * Nn + i0 + wave * 16 + ln)) * Dn + lg * 8;
#pragma unroll
        for (int kp = 0; kp < 2; ++kp) {
            floatx4 f0 = *(const floatx4*)(qp + kp * 32);
            floatx4 f1 = *(const floatx4*)(qp + kp * 32 + 4);
            union { short8 s; unsigned u[4]; } qq;
            qq.u[0] = cvt_pk_bf16(f0[0], f0[1]);
            qq.u[1] = cvt_pk_bf16(f0[2], f0[3]);
            qq.u[2] = cvt_pk_bf16(f1[0], f1[1]);
            qq.u[3] = cvt_pk_bf16(f1[2], f1[3]);
            qa[kp] = qq.s;
        }
    }

    short8 ones;
#pragma unroll
    for (int i = 0; i < 8; ++i) ones[i] = (short)0x3F80;   // bf16 1.0

    floatx4 o_acc[4];
#pragma unroll
    for (int dt = 0; dt < 4; ++dt) o_acc[dt] = (floatx4){0.f, 0.f, 0.f, 0.f};
    floatx4 l_acc = {0.f, 0.f, 0.f, 0.f};

    const int irow0 = i0 + wave * 16;
    const long bias_base = ((long)bh) << 20;           // bh * N * N

    // ---- register prefetch buffers (tile jt staged from regs loaded at jt-1) ----
    floatx4 kpf[4];      // 16 floats: K tile slice for this thread
    float   vpf[16];     // 16 floats: V tile slice (strided rows, col=lane)
    float   bv[4][4];    // bias values for this thread's P fragment

    // ---- prologue: prefetch tile 0 ----
    {
        const float* kb = kk + ((long)(bh * Nn)) * Dn;
#pragma unroll
        for (int it = 0; it < 4; ++it)
            kpf[it] = *(const floatx4*)(kb + it * 1024 + tid * 4);
        const float* vb = v + ((long)(bh * Nn)) * Dn;
#pragma unroll
        for (int r = 0; r < 16; ++r)
            vpf[r] = vb[(wave * 16 + r) * Dn + lane];      // coalesced across lanes
#pragma unroll
        for (int nt = 0; nt < 4; ++nt)
#pragma unroll
            for (int r = 0; r < 4; ++r)
                bv[nt][r] = bias[bias_base + (long)(irow0 + lg * 4 + r) * Nn
                                 + nt * 16 + ln];
    }

    for (int jt = 0; jt <= qt; ++jt) {
        const int j0 = jt * 64;

        __syncthreads();                     // prior-tile LDS readers done

        // ---- stage K tile from regs: cvt + ds_write only ----
#pragma unroll
        for (int it = 0; it < 4; ++it) {
            const int e = it * 1024 + tid * 4;
            uint2v w;
            w.x = cvt_pk_bf16(kpf[it][0], kpf[it][1]);
            w.y = cvt_pk_bf16(kpf[it][2], kpf[it][3]);
            *(uint2v*)&k_s[e >> 6][e & 63] = w;
        }
        // ---- stage V tile transposed from regs ----
        {
            uint4v lo, hi;
            lo.x = cvt_pk_bf16(vpf[0],  vpf[1]);
            lo.y = cvt_pk_bf16(vpf[2],  vpf[3]);
            lo.z = cvt_pk_bf16(vpf[4],  vpf[5]);
            lo.w = cvt_pk_bf16(vpf[6],  vpf[7]);
            hi.x = cvt_pk_bf16(vpf[8],  vpf[9]);
            hi.y = cvt_pk_bf16(vpf[10], vpf[11]);
            hi.z = cvt_pk_bf16(vpf[12], vpf[13]);
            hi.w = cvt_pk_bf16(vpf[14], vpf[15]);
            *(uint4v*)&vt_s[lane][wave * 16]     = lo;
            *(uint4v*)&vt_s[lane][wave * 16 + 8] = hi;
        }

        __syncthreads();                     // tile jt visible to all waves

        // ---- issue K/V prefetch for tile jt+1 (covered by full compute) ----
        if (jt < qt) {
            const float* kbn = kk + ((long)(bh * Nn + j0 + 64)) * Dn;
#pragma unroll
            for (int it = 0; it < 4; ++it)
                kpf[it] = *(const floatx4*)(kbn + it * 1024 + tid * 4);
            const float* vbn = v + ((long)(bh * Nn + j0 + 64)) * Dn;
#pragma unroll
            for (int r = 0; r < 16; ++r)
                vpf[r] = vbn[(wave * 16 + r) * Dn + lane];
        }

        // ---- S = Q K^T (8 mfma) ----
        floatx4 sfr[4];
#pragma unroll
        for (int nt = 0; nt < 4; ++nt) {
            short8 b0 = *(const short8*)&k_s[nt * 16 + ln][lg * 8];
            short8 b1 = *(const short8*)&k_s[nt * 16 + ln][32 + lg * 8];
            floatx4 acc = {0.f, 0.f, 0.f, 0.f};
            acc = __builtin_amdgcn_mfma_f32_16x16x32_bf16(qa[0], b0, acc, 0, 0, 0);
            acc = __builtin_amdgcn_mfma_f32_16x16x32_bf16(qa[1], b1, acc, 0, 0, 0);
            sfr[nt] = acc;
        }

        // ---- P = exp(scale*S + bias), causal-masked on diagonal tile ----
        const bool diag = (jt == qt);
#pragma unroll
        for (int nt = 0; nt < 4; ++nt) {
#pragma unroll
            for (int r = 0; r < 4; ++r) {
                float sv = sfr[nt][r] * 0.125f + bv[nt][r];
                if (diag) {
                    const int i_ = irow0 + lg * 4 + r;
                    const int j_ = j0 + nt * 16 + ln;
                    sv = (j_ > i_) ? NEG_BIG : sv;
                }
                const float p  = __expf(sv);
                const float po = __shfl_xor(p, 1);
                if (!(lane & 1)) {           // even lane packs (ln, ln+1) -> b32
                    *(unsigned*)&p_s[wave][lg * 4 + r][nt * 16 + ln] =
                        cvt_pk_bf16(p, po);
                }
            }
        }

        // ---- issue bias prefetch for tile jt+1 (bv now dead) ----
        if (jt < qt) {
            const int j1 = j0 + 64;
#pragma unroll
            for (int nt = 0; nt < 4; ++nt)
#pragma unroll
                for (int r = 0; r < 4; ++r)
                    bv[nt][r] = bias[bias_base + (long)(irow0 + lg * 4 + r) * Nn
                                     + j1 + nt * 16 + ln];
        }

        // ---- P A-frags (wave-local LDS round trip) ----
        const short8 pa0 = *(const short8*)&p_s[wave][ln][lg * 8];
        const short8 pa1 = *(const short8*)&p_s[wave][ln][32 + lg * 8];

        // ---- l += P . ones (row-sums, same C layout as O) ----
        l_acc = __builtin_amdgcn_mfma_f32_16x16x32_bf16(pa0, ones, l_acc, 0, 0, 0);
        l_acc = __builtin_amdgcn_mfma_f32_16x16x32_bf16(pa1, ones, l_acc, 0, 0, 0);

        // ---- O += P V (8 mfma) ----
#pragma unroll
        for (int dt = 0; dt < 4; ++dt) {
            short8 vb0 = *(const short8*)&vt_s[dt * 16 + ln][lg * 8];
            short8 vb1 = *(const short8*)&vt_s[dt * 16 + ln][32 + lg * 8];
            o_acc[dt] = __builtin_amdgcn_mfma_f32_16x16x32_bf16(pa0, vb0, o_acc[dt], 0, 0, 0);
            o_acc[dt] = __builtin_amdgcn_mfma_f32_16x16x32_bf16(pa1, vb1, o_acc[dt], 0, 0, 0);
        }
    }

    // ---- epilogue: out = O / l, fp32 stores ----
#pragma unroll
    for (int r = 0; r < 4; ++r) {
        const float linv = 1.0f / l_acc[r];
        const long orow = ((long)(bh * Nn + irow0 + lg * 4 + r)) * Dn;
#pragma unroll
        for (int dt = 0; dt < 4; ++dt)
            out[orow + dt * 16 + ln] = o_acc[dt][r] * linv;
    }
}

extern "C" void kernel_launch(void* const* d_in, const int* in_sizes, int n_in,
                              void* d_out, int out_size, void* d_ws, size_t ws_size,
                              hipStream_t stream) {
    const float* q    = (const float*)d_in[0];
    const float* k    = (const float*)d_in[1];
    const float* v    = (const float*)d_in[2];
    const float* bias = (const float*)d_in[3];
    float* out = (float*)d_out;

    dim3 grid(BHn * 16);   // 64 heads x 16 q-tiles of 64 rows
    dim3 block(256);
    attend_mfma<<<grid, block, 0, stream>>>(q, k, v, bias, out);
}